// Round 1
// baseline (168.543 us; speedup 1.0000x reference)
//
#include <hip/hip_runtime.h>
#include <hip/hip_bf16.h>

// HMM forward, chunk-parallel + MFMA. B=64, T=4096, S=64.
// C_CH=64 chunks of LL=64, WARM=24 (R4-validated geometry).
//
// R1 change vs previous best: shuffle-free recurrence step.
// The old step fed u as the B-operand of mfma_f32_16x16x32_bf16, whose
// fragment wants i = 8q+e per lane, while the D-layout state holds
// j = 4q+r -> 17 ds_bpermute + 8 cndmask per step ON the serial chain
// (~1700 cy/step measured, SQ_LDS_BANK_CONFLICT 721K). With
// mfma_f32_16x16x16_bf16 (K=16) the B-layout is B[k=4q+e][n=lane&15],
// which IS the D-layout of the previous step:
//   al2[kb] holds alpha2[task=lane&15][j = 16*kb + 4q + r]
//   B_kb    = pack_bf16(exp2(al2[kb] - M2))            (no shuffles)
//   A_jt,kb[m=p][k=4q+e] = exp(T[16kb+4q+e][16jt+p])   (invariant, 32 VGPR)
//   d[jt]   = sum_kb mfma16(A[jt][kb], B[kb])  -> D back in al2 layout.
// Only cross-lane op left: 1 bpermute/step for the per-task shift M2,
// issued after jt=0's update and consumed next step (latency hidden).
// M2 cancels exactly in the math, so its schedule is semantics-free.
//
// Phase A (MFMA): 256 waves; each wave owns 16 tasks (b fixed, c = 16*cg+n).
//   c=0 runs the same 88-step schedule with t0=-25 (reads wrapped via &4095,
//   garbage warm); at s==25 its lanes override alpha := true alpha0=emis[0]
//   (+ wave-uniform M2 refresh), so its writes t=0..63 are exact.
// Phase C: delta prefix-sum (from ws scalars) + float4 RMW correction + log_Z.

#define BB 64
#define TT 4096
#define SS 64
#define C_CH 64
#define LL 64
#define WARM 24

typedef __attribute__((ext_vector_type(4))) short bh4;
typedef __attribute__((ext_vector_type(4))) float f32x4;

#define LOG2E 1.44269504088896340736f
#define LN2F  0.69314718055994530942f

__device__ __forceinline__ float fexp2(float x) {
#if __has_builtin(__builtin_amdgcn_exp2f)
    return __builtin_amdgcn_exp2f(x);
#else
    return exp2f(x);
#endif
}
__device__ __forceinline__ float flog2(float x) {
#if __has_builtin(__builtin_amdgcn_logf)
    return __builtin_amdgcn_logf(x);
#else
    return log2f(x);
#endif
}
__device__ __forceinline__ float bpermf(int idx, float v) {
    return __uint_as_float((unsigned)__builtin_amdgcn_ds_bpermute(idx, (int)__float_as_uint(v)));
}
__device__ __forceinline__ int pack_bf16(float x, float y) {
    __hip_bfloat162 h = __float22bfloat162_rn(make_float2(x, y));
    int r; __builtin_memcpy(&r, &h, 4); return r;
}
union PB2 { int i[2]; bh4 v; };

__device__ __forceinline__ f32x4 mfma16(bh4 a, bh4 b, f32x4 c) {
#if __has_builtin(__builtin_amdgcn_mfma_f32_16x16x16bf16_1k)
    return __builtin_amdgcn_mfma_f32_16x16x16bf16_1k(a, b, c, 0, 0, 0);
#else
    asm("v_mfma_f32_16x16x16_bf16 %0, %1, %2, %0" : "+v"(c) : "v"(a), "v"(b));
    return c;
#endif
}

// One recurrence step for 16 tasks, shuffle-free (see header comment).
// Returns M2 for the NEXT step = broadcast of post-step alpha2[task][0];
// the bpermute is issued after jt=0 so its latency hides under jt=1..3.
__device__ __forceinline__ float do_step(f32x4 (&al2)[4], const f32x4 (&er)[4],
                                         const bh4 (&Af)[4][4],
                                         float M2, int idxM) {
    // B-fragments: B_kb[k=4q+e][n=p] = exp2(alpha2[p][16kb+4q+e] - M2[p]).
    bh4 Bf[4];
    #pragma unroll
    for (int kb = 0; kb < 4; ++kb) {
        PB2 pb;
        pb.i[0] = pack_bf16(fexp2(al2[kb].x - M2), fexp2(al2[kb].y - M2));
        pb.i[1] = pack_bf16(fexp2(al2[kb].z - M2), fexp2(al2[kb].w - M2));
        Bf[kb] = pb.v;
    }

    float M2n = 0.f;
    #pragma unroll
    for (int jt = 0; jt < 4; ++jt) {
        f32x4 d = {0.f, 0.f, 0.f, 0.f};
        #pragma unroll
        for (int kb = 0; kb < 4; ++kb)
            d = mfma16(Af[jt][kb], Bf[kb], d);
        // alpha2' = M2 + emis*log2e + log2(s); D layout == al2 layout.
        al2[jt].x = fmaf(er[jt].x, LOG2E, M2) + flog2(d.x);
        al2[jt].y = fmaf(er[jt].y, LOG2E, M2) + flog2(d.y);
        al2[jt].z = fmaf(er[jt].z, LOG2E, M2) + flog2(d.z);
        al2[jt].w = fmaf(er[jt].w, LOG2E, M2) + flog2(d.w);
        if (jt == 0) M2n = bpermf(idxM, al2[0].x);
    }
    return M2n;
}

__device__ __forceinline__ void load_row(f32x4 (&dst)[4],
                                         const float* __restrict__ eb,
                                         int t, int off) {
    const float* p = eb + (t & (TT - 1)) * SS + off;
    #pragma unroll
    for (int jt = 0; jt < 4; ++jt)
        dst[jt] = *(const f32x4*)(p + 16 * jt);
}

__global__ __launch_bounds__(64)
__attribute__((amdgpu_waves_per_eu(1, 1)))
void hmm_phaseA(const float* __restrict__ trans,
                const float* __restrict__ emis,
                float* __restrict__ out,
                float* __restrict__ ws_warm,
                float* __restrict__ ws_bound) {
    const int lane = threadIdx.x;
    const int n = lane & 15, q = lane >> 4;
    const int w = blockIdx.x;                  // 0..255
    const int b = w >> 2, cg = w & 3;
    const int c = 16 * cg + n;                 // this lane's task
    const bool is_c0 = (c == 0);
    const int off = 4 * q;

    // A-fragments (K=16): A_jt,kb[m=n][k=4q+e] = exp(T[16kb+4q+e][16jt+n]).
    bh4 Af[4][4];
    #pragma unroll
    for (int jt = 0; jt < 4; ++jt)
        #pragma unroll
        for (int kb = 0; kb < 4; ++kb) {
            float v0 = __expf(trans[(16 * kb + 4 * q + 0) * SS + 16 * jt + n]);
            float v1 = __expf(trans[(16 * kb + 4 * q + 1) * SS + 16 * jt + n]);
            float v2 = __expf(trans[(16 * kb + 4 * q + 2) * SS + 16 * jt + n]);
            float v3 = __expf(trans[(16 * kb + 4 * q + 3) * SS + 16 * jt + n]);
            PB2 pb;
            pb.i[0] = pack_bf16(v0, v1);
            pb.i[1] = pack_bf16(v2, v3);
            Af[jt][kb] = pb.v;
        }

    const int idxM = n << 2;                   // broadcast lane p -> all q

    const float* eb = emis + (size_t)b * TT * SS;
    float*       ob = out  + (size_t)b * TT * SS;

    const int t0 = LL * c - (WARM + 1);        // c=0 => -25 (wrapped reads)

    // Init: alpha2 = emis[t0]*log2e (pseudo); keep row 0 for the c0 override.
    f32x4 al2[4], e0[4], ebuf[4][4];
    load_row(al2, eb, t0, off);
    #pragma unroll
    for (int jt = 0; jt < 4; ++jt) al2[jt] = al2[jt] * LOG2E;
    load_row(e0, eb, 0, off);
    #pragma unroll
    for (int k = 0; k < 4; ++k) load_row(ebuf[k], eb, t0 + 1 + k, off);

    float M2 = bpermf(idxM, al2[0].x);

    // Warm-up: s = 1..24, no stores.
    #pragma unroll 1
    for (int g = 0; g < 6; ++g) {
        #pragma unroll
        for (int k = 0; k < 4; ++k) {
            int s = 4 * g + k + 1;
            f32x4 er[4];
            #pragma unroll
            for (int jt = 0; jt < 4; ++jt) er[jt] = ebuf[k][jt];
            load_row(ebuf[k], eb, t0 + s + 4, off);
            M2 = do_step(al2, er, Af, M2, idxM);
        }
    }
    // Boundary (uncorrected) alpha at t = 64c-1: lane n (q=0) holds j=0.
    if (lane < 16)
        ws_warm[b * C_CH + 16 * cg + lane] = al2[0].x * LN2F;

    // Main: s = 25..88, writes t = t0+s = 64c .. 64c+63.
    #pragma unroll 1
    for (int g = 0; g < 16; ++g) {
        #pragma unroll
        for (int k = 0; k < 4; ++k) {
            int s = 25 + 4 * g + k;
            f32x4 er[4];
            #pragma unroll
            for (int jt = 0; jt < 4; ++jt) er[jt] = ebuf[k][jt];
            load_row(ebuf[k], eb, t0 + s + 4, off);
            M2 = do_step(al2, er, Af, M2, idxM);
            if (k == 0 && g == 0) {
                if (is_c0) {
                    // chunk 0: replace garbage warm result with true alpha0.
                    #pragma unroll
                    for (int jt = 0; jt < 4; ++jt) al2[jt] = e0[jt] * LOG2E;
                }
                if (cg == 0)   // wave-uniform: refresh M2 after the override
                    M2 = bpermf(idxM, al2[0].x);
            }
            float* p = ob + (t0 + s) * SS + off;
            #pragma unroll
            for (int jt = 0; jt < 4; ++jt)
                *(f32x4*)(p + 16 * jt) = al2[jt] * LN2F;
        }
    }
    if (lane < 16)
        ws_bound[b * C_CH + 16 * cg + lane] = al2[0].x * LN2F;
}

// Correction: redundant per-block prefix sum of deltas (ws scalars only),
// float4 RMW of the chunk, block (b, C-1) emits log_Z.
__global__ __launch_bounds__(256)
void hmm_phaseC(float* __restrict__ out,
                const float* __restrict__ ws_warm,
                const float* __restrict__ ws_bound) {
    const int b = blockIdx.x, c = blockIdx.y, tid = threadIdx.x;
    __shared__ float sdelta;

    if (tid < 64) {
        float d = 0.f;
        if (tid > 0 && tid < C_CH)
            d = ws_bound[b * C_CH + tid - 1] - ws_warm[b * C_CH + tid];
        #pragma unroll
        for (int off = 1; off < C_CH; off <<= 1) {
            float v = __shfl_up(d, off, 64);
            if (tid >= off) d += v;
        }
        float dc = __shfl(d, c, 64);
        if (tid == 0) sdelta = dc;
    }
    __syncthreads();
    const float delta = sdelta;

    float4* p4 = (float4*)(out + (size_t)b * TT * SS + (size_t)c * LL * SS);
    float4 last;
    #pragma unroll
    for (int i = 0; i < 4; ++i) {
        int idx = tid + 256 * i;               // 4*256 = 1024 float4 = LL*SS
        float4 v = p4[idx];
        v.x += delta; v.y += delta; v.z += delta; v.w += delta;
        p4[idx] = v;
        last = v;                              // i==3, tid 240..255 => row T-1
    }

    if (c == C_CH - 1 && tid >= 240) {
        float mx = fmaxf(fmaxf(last.x, last.y), fmaxf(last.z, last.w));
        #pragma unroll
        for (int off = 8; off >= 1; off >>= 1)
            mx = fmaxf(mx, __shfl_xor(mx, off, 64));
        float sv = __expf(last.x - mx) + __expf(last.y - mx)
                 + __expf(last.z - mx) + __expf(last.w - mx);
        #pragma unroll
        for (int off = 8; off >= 1; off >>= 1)
            sv += __shfl_xor(sv, off, 64);
        if (tid == 240)
            out[(size_t)BB * TT * SS + b] = mx + __logf(sv);
    }
}

extern "C" void kernel_launch(void* const* d_in, const int* in_sizes, int n_in,
                              void* d_out, int out_size, void* d_ws, size_t ws_size,
                              hipStream_t stream) {
    const float* trans = (const float*)d_in[0];   // (S,S)
    const float* emis  = (const float*)d_in[1];   // (B,T,S)
    // d_in[2] = seq_lens — unused by the reference.
    float* out = (float*)d_out;                   // alpha (B,T,S) ++ log_Z (B,)

    float* ws_warm  = (float*)d_ws;               // B*C floats
    float* ws_bound = ws_warm + BB * C_CH;        // B*C floats

    hmm_phaseA<<<dim3(BB * 4), dim3(64), 0, stream>>>(trans, emis, out,
                                                      ws_warm, ws_bound);
    hmm_phaseC<<<dim3(BB, C_CH), dim3(256), 0, stream>>>(out, ws_warm, ws_bound);
}

// Round 2
// 155.059 us; speedup vs baseline: 1.0870x; 1.0870x over previous
//
#include <hip/hip_runtime.h>
#include <hip/hip_bf16.h>

// HMM forward, chunk-parallel + MFMA. B=64, T=4096, S=64.
//
// R2 change vs R1: attack exposed global-load latency (R1 post-mortem:
// 1530 cy/step with VALUBusy 10%, MfmaUtil 3.5%, LDS conflicts 0 -> wave
// stalled ~86% on scattered emission-row loads at 1 wave/CU, prefetch 4).
//   - LL=32, C_CH=128 -> 512 waves (2 blocks/CU), 57 steps/wave (was 89).
//     WARM=24 unchanged, so per-boundary accuracy is unchanged.
//   - Prefetch depth 8 (ebuf[8][4], +64 VGPR) -> step >= latency/8.
//   - MFMA chain split into 2 accumulators (4 dependent -> 2 + add).
//
// Recurrence step (R1, shuffle-free): K=16 MFMA layout closure.
//   al2[kb] holds alpha2[task=lane&15][j = 16*kb + 4q + r]
//   B_kb    = pack_bf16(exp2(al2[kb] - M2))            (no shuffles)
//   A_jt,kb[m=p][k=4q+e] = exp(T[16kb+4q+e][16jt+p])   (invariant, 32 VGPR)
//   d[jt]   = sum_kb mfma16(A[jt][kb], B[kb])  -> D back in al2 layout.
// Only cross-lane op: 1 bpermute/step for the per-task shift M2 (hidden
// under jt=1..3; M2 cancels exactly in the math).
//
// Phase A: 512 waves; each wave owns 16 tasks (b fixed, c = 16*cg+n).
//   c=0 runs the same 57-step schedule with t0=-25 (reads wrapped via &4095,
//   garbage warm); at s==25 its lanes override alpha := true alpha0=emis[0]
//   (+ wave-uniform M2 refresh), so its writes t=0..31 are exact.
// Phase C: delta prefix-sum (LDS scan over 128) + float4 RMW + log_Z.

#define BB 64
#define TT 4096
#define SS 64
#define C_CH 128
#define LL 32
#define WARM 24
#define PF 8

typedef __attribute__((ext_vector_type(4))) short bh4;
typedef __attribute__((ext_vector_type(4))) float f32x4;

#define LOG2E 1.44269504088896340736f
#define LN2F  0.69314718055994530942f

__device__ __forceinline__ float fexp2(float x) {
#if __has_builtin(__builtin_amdgcn_exp2f)
    return __builtin_amdgcn_exp2f(x);
#else
    return exp2f(x);
#endif
}
__device__ __forceinline__ float flog2(float x) {
#if __has_builtin(__builtin_amdgcn_logf)
    return __builtin_amdgcn_logf(x);
#else
    return log2f(x);
#endif
}
__device__ __forceinline__ float bpermf(int idx, float v) {
    return __uint_as_float((unsigned)__builtin_amdgcn_ds_bpermute(idx, (int)__float_as_uint(v)));
}
__device__ __forceinline__ int pack_bf16(float x, float y) {
    __hip_bfloat162 h = __float22bfloat162_rn(make_float2(x, y));
    int r; __builtin_memcpy(&r, &h, 4); return r;
}
union PB2 { int i[2]; bh4 v; };

__device__ __forceinline__ f32x4 mfma16(bh4 a, bh4 b, f32x4 c) {
#if __has_builtin(__builtin_amdgcn_mfma_f32_16x16x16bf16_1k)
    return __builtin_amdgcn_mfma_f32_16x16x16bf16_1k(a, b, c, 0, 0, 0);
#else
    asm("v_mfma_f32_16x16x16_bf16 %0, %1, %2, %0" : "+v"(c) : "v"(a), "v"(b));
    return c;
#endif
}

// One recurrence step for 16 tasks, shuffle-free (see header comment).
// Returns M2 for the NEXT step = broadcast of post-step alpha2[task][0];
// the bpermute is issued after jt=0 so its latency hides under jt=1..3.
__device__ __forceinline__ float do_step(f32x4 (&al2)[4], const f32x4 (&er)[4],
                                         const bh4 (&Af)[4][4],
                                         float M2, int idxM) {
    // B-fragments: B_kb[k=4q+e][n=p] = exp2(alpha2[p][16kb+4q+e] - M2[p]).
    bh4 Bf[4];
    #pragma unroll
    for (int kb = 0; kb < 4; ++kb) {
        PB2 pb;
        pb.i[0] = pack_bf16(fexp2(al2[kb].x - M2), fexp2(al2[kb].y - M2));
        pb.i[1] = pack_bf16(fexp2(al2[kb].z - M2), fexp2(al2[kb].w - M2));
        Bf[kb] = pb.v;
    }

    float M2n = 0.f;
    #pragma unroll
    for (int jt = 0; jt < 4; ++jt) {
        f32x4 d0 = {0.f, 0.f, 0.f, 0.f};
        f32x4 d1 = {0.f, 0.f, 0.f, 0.f};
        d0 = mfma16(Af[jt][0], Bf[0], d0);
        d1 = mfma16(Af[jt][1], Bf[1], d1);
        d0 = mfma16(Af[jt][2], Bf[2], d0);
        d1 = mfma16(Af[jt][3], Bf[3], d1);
        f32x4 d = d0 + d1;
        // alpha2' = M2 + emis*log2e + log2(s); D layout == al2 layout.
        al2[jt].x = fmaf(er[jt].x, LOG2E, M2) + flog2(d.x);
        al2[jt].y = fmaf(er[jt].y, LOG2E, M2) + flog2(d.y);
        al2[jt].z = fmaf(er[jt].z, LOG2E, M2) + flog2(d.z);
        al2[jt].w = fmaf(er[jt].w, LOG2E, M2) + flog2(d.w);
        if (jt == 0) M2n = bpermf(idxM, al2[0].x);
    }
    return M2n;
}

__device__ __forceinline__ void load_row(f32x4 (&dst)[4],
                                         const float* __restrict__ eb,
                                         int t, int off) {
    const float* p = eb + (t & (TT - 1)) * SS + off;
    #pragma unroll
    for (int jt = 0; jt < 4; ++jt)
        dst[jt] = *(const f32x4*)(p + 16 * jt);
}

__global__ __launch_bounds__(64)
__attribute__((amdgpu_waves_per_eu(1, 1)))
void hmm_phaseA(const float* __restrict__ trans,
                const float* __restrict__ emis,
                float* __restrict__ out,
                float* __restrict__ ws_warm,
                float* __restrict__ ws_bound) {
    const int lane = threadIdx.x;
    const int n = lane & 15, q = lane >> 4;
    const int w = blockIdx.x;                  // 0..511
    const int b = w >> 3, cg = w & 7;
    const int c = 16 * cg + n;                 // this lane's task
    const bool is_c0 = (c == 0);
    const int off = 4 * q;

    // A-fragments (K=16): A_jt,kb[m=n][k=4q+e] = exp(T[16kb+4q+e][16jt+n]).
    bh4 Af[4][4];
    #pragma unroll
    for (int jt = 0; jt < 4; ++jt)
        #pragma unroll
        for (int kb = 0; kb < 4; ++kb) {
            float v0 = __expf(trans[(16 * kb + 4 * q + 0) * SS + 16 * jt + n]);
            float v1 = __expf(trans[(16 * kb + 4 * q + 1) * SS + 16 * jt + n]);
            float v2 = __expf(trans[(16 * kb + 4 * q + 2) * SS + 16 * jt + n]);
            float v3 = __expf(trans[(16 * kb + 4 * q + 3) * SS + 16 * jt + n]);
            PB2 pb;
            pb.i[0] = pack_bf16(v0, v1);
            pb.i[1] = pack_bf16(v2, v3);
            Af[jt][kb] = pb.v;
        }

    const int idxM = n << 2;                   // broadcast lane p -> all q

    const float* eb = emis + (size_t)b * TT * SS;
    float*       ob = out  + (size_t)b * TT * SS;

    const int t0 = LL * c - (WARM + 1);        // c=0 => -25 (wrapped reads)

    // Init: alpha2 = emis[t0]*log2e (pseudo); keep row 0 for the c0 override.
    f32x4 al2[4], e0[4], ebuf[PF][4];
    load_row(al2, eb, t0, off);
    #pragma unroll
    for (int jt = 0; jt < 4; ++jt) al2[jt] = al2[jt] * LOG2E;
    load_row(e0, eb, 0, off);
    #pragma unroll
    for (int k = 0; k < PF; ++k) load_row(ebuf[k], eb, t0 + 1 + k, off);

    float M2 = bpermf(idxM, al2[0].x);

    // Warm-up: s = 1..24 (3 groups of PF=8), no stores. slot = k.
    #pragma unroll 1
    for (int g = 0; g < 3; ++g) {
        #pragma unroll
        for (int k = 0; k < PF; ++k) {
            int s = PF * g + k + 1;
            f32x4 er[4];
            #pragma unroll
            for (int jt = 0; jt < 4; ++jt) er[jt] = ebuf[k][jt];
            load_row(ebuf[k], eb, t0 + s + PF, off);
            M2 = do_step(al2, er, Af, M2, idxM);
        }
    }
    // Boundary (uncorrected) alpha at t = 32c-1: lane n (q=0) holds j=0.
    if (lane < 16)
        ws_warm[b * C_CH + 16 * cg + lane] = al2[0].x * LN2F;

    // Main: s = 25..56, writes t = t0+s = 32c .. 32c+31. slot = k.
    #pragma unroll 1
    for (int g = 0; g < 4; ++g) {
        #pragma unroll
        for (int k = 0; k < PF; ++k) {
            int s = WARM + 1 + PF * g + k;
            f32x4 er[4];
            #pragma unroll
            for (int jt = 0; jt < 4; ++jt) er[jt] = ebuf[k][jt];
            load_row(ebuf[k], eb, t0 + s + PF, off);
            M2 = do_step(al2, er, Af, M2, idxM);
            if (k == 0 && g == 0) {
                if (is_c0) {
                    // chunk 0: replace garbage warm result with true alpha0.
                    #pragma unroll
                    for (int jt = 0; jt < 4; ++jt) al2[jt] = e0[jt] * LOG2E;
                }
                if (cg == 0)   // wave-uniform: refresh M2 after the override
                    M2 = bpermf(idxM, al2[0].x);
            }
            float* p = ob + (t0 + s) * SS + off;
            #pragma unroll
            for (int jt = 0; jt < 4; ++jt)
                *(f32x4*)(p + 16 * jt) = al2[jt] * LN2F;
        }
    }
    if (lane < 16)
        ws_bound[b * C_CH + 16 * cg + lane] = al2[0].x * LN2F;
}

// Correction: redundant per-block prefix sum of deltas (ws scalars only,
// LDS Hillis-Steele over C_CH=128), float4 RMW of the chunk, block
// (b, C-1) emits log_Z.
__global__ __launch_bounds__(256)
void hmm_phaseC(float* __restrict__ out,
                const float* __restrict__ ws_warm,
                const float* __restrict__ ws_bound) {
    const int b = blockIdx.x, c = blockIdx.y, tid = threadIdx.x;
    __shared__ float sd[C_CH];

    if (tid < C_CH) {
        float d = 0.f;
        if (tid > 0)
            d = ws_bound[b * C_CH + tid - 1] - ws_warm[b * C_CH + tid];
        sd[tid] = d;
    }
    __syncthreads();
    #pragma unroll
    for (int off = 1; off < C_CH; off <<= 1) {
        float v = 0.f;
        if (tid >= off && tid < C_CH) v = sd[tid - off];
        __syncthreads();
        if (tid >= off && tid < C_CH) sd[tid] += v;
        __syncthreads();
    }
    const float delta = sd[c];

    float4* p4 = (float4*)(out + (size_t)b * TT * SS + (size_t)c * LL * SS);
    float4 last;
    #pragma unroll
    for (int i = 0; i < 2; ++i) {
        int idx = tid + 256 * i;               // 2*256 = 512 float4 = LL*SS
        float4 v = p4[idx];
        v.x += delta; v.y += delta; v.z += delta; v.w += delta;
        p4[idx] = v;
        last = v;                              // i==1, tid 240..255 => row T-1
    }

    if (c == C_CH - 1 && tid >= 240) {
        float mx = fmaxf(fmaxf(last.x, last.y), fmaxf(last.z, last.w));
        #pragma unroll
        for (int off = 8; off >= 1; off >>= 1)
            mx = fmaxf(mx, __shfl_xor(mx, off, 64));
        float sv = __expf(last.x - mx) + __expf(last.y - mx)
                 + __expf(last.z - mx) + __expf(last.w - mx);
        #pragma unroll
        for (int off = 8; off >= 1; off >>= 1)
            sv += __shfl_xor(sv, off, 64);
        if (tid == 240)
            out[(size_t)BB * TT * SS + b] = mx + __logf(sv);
    }
}

extern "C" void kernel_launch(void* const* d_in, const int* in_sizes, int n_in,
                              void* d_out, int out_size, void* d_ws, size_t ws_size,
                              hipStream_t stream) {
    const float* trans = (const float*)d_in[0];   // (S,S)
    const float* emis  = (const float*)d_in[1];   // (B,T,S)
    // d_in[2] = seq_lens — unused by the reference.
    float* out = (float*)d_out;                   // alpha (B,T,S) ++ log_Z (B,)

    float* ws_warm  = (float*)d_ws;               // B*C floats
    float* ws_bound = ws_warm + BB * C_CH;        // B*C floats

    hmm_phaseA<<<dim3(BB * 8), dim3(64), 0, stream>>>(trans, emis, out,
                                                      ws_warm, ws_bound);
    hmm_phaseC<<<dim3(BB, C_CH), dim3(256), 0, stream>>>(out, ws_warm, ws_bound);
}

// Round 3
// 155.042 us; speedup vs baseline: 1.0871x; 1.0001x over previous
//
#include <hip/hip_runtime.h>
#include <hip/hip_bf16.h>

// HMM forward, chunk-parallel + MFMA. B=64, T=4096, S=64.
//
// R3 change vs R2: coalesce the HBM streams. R2 post-mortem: per-step
// emission loads/stores touched 16 x 64B segments at 8KB stride (one per
// task) -> device stream = 8192 interleaved 256B streams -> HBM at ~40%
// efficiency (3 TB/s), phaseA AT the scattered-access roofline (44us for
// 132MB). Fix: stage through LDS so every global instruction moves 1KB
// CONTIGUOUS of one task:
//   loads : global_load_lds dwordx4 (lane x 16B linear dest), source
//           address carries the task-XOR unit swizzle (u_src = (l&15)^i)
//           so per-step ds_read_b128 redistribution is bank-minimal.
//   stores: steps ds_write al2 into a 16KB staging tile (same swizzle),
//           end of each 4-step phase does 16 coalesced 1KB stores.
//   waits : counted s_waitcnt vmcnt(16/32) (never 0), 2-phase lead,
//           3 load slots x 16KB (m201 T3/T4 pattern). LDS 64KB, 2 blk/CU.
//
// Recurrence step (R1/R2, shuffle-free): K=16 MFMA layout closure.
//   al2[kb] holds alpha2[task=lane&15][j = 16*kb + 4q + r]
//   B_kb    = pack_bf16(exp2(al2[kb] - M2))            (no shuffles)
//   A_jt,kb[m=p][k=4q+e] = exp(T[16kb+4q+e][16jt+p])   (invariant, 32 VGPR)
//   d[jt]   = sum_kb mfma16(A[jt][kb], B[kb])  -> D back in al2 layout.
// One bpermute/step for the per-task shift M2 (cancels exactly in math).
//
// Geometry: LL=32, C_CH=128, WARM=24, 512 waves; 14 phases x 4 steps
// (warm p=0..5, main p=6..13). Phase p, step r -> s = 4p+r+1, consuming
// row 32c-24+4p+r; c=0 wraps (&4095) during warm (garbage), overridden
// to true alpha0 at s==25. Phase C: scan + float4 RMW + log_Z (unchanged).

#define BB 64
#define TT 4096
#define SS 64
#define C_CH 128
#define LL 32
#define WARM 24
#define SLOTF 4096          // floats per load slot (16 tasks x 4 rows x 64)
#define OUTF  12288         // float offset of out staging tile

typedef __attribute__((ext_vector_type(4))) short bh4;
typedef __attribute__((ext_vector_type(4))) float f32x4;

#define LOG2E 1.44269504088896340736f
#define LN2F  0.69314718055994530942f

#define WAITV(N) asm volatile("s_waitcnt vmcnt(" #N ")" ::: "memory")

__device__ __forceinline__ float fexp2(float x) {
#if __has_builtin(__builtin_amdgcn_exp2f)
    return __builtin_amdgcn_exp2f(x);
#else
    return exp2f(x);
#endif
}
__device__ __forceinline__ float flog2(float x) {
#if __has_builtin(__builtin_amdgcn_logf)
    return __builtin_amdgcn_logf(x);
#else
    return log2f(x);
#endif
}
__device__ __forceinline__ float bpermf(int idx, float v) {
    return __uint_as_float((unsigned)__builtin_amdgcn_ds_bpermute(idx, (int)__float_as_uint(v)));
}
__device__ __forceinline__ int pack_bf16(float x, float y) {
    __hip_bfloat162 h = __float22bfloat162_rn(make_float2(x, y));
    int r; __builtin_memcpy(&r, &h, 4); return r;
}
union PB2 { int i[2]; bh4 v; };

__device__ __forceinline__ f32x4 mfma16(bh4 a, bh4 b, f32x4 c) {
#if __has_builtin(__builtin_amdgcn_mfma_f32_16x16x16bf16_1k)
    return __builtin_amdgcn_mfma_f32_16x16x16bf16_1k(a, b, c, 0, 0, 0);
#else
    asm("v_mfma_f32_16x16x16_bf16 %0, %1, %2, %0" : "+v"(c) : "v"(a), "v"(b));
    return c;
#endif
}

// One recurrence step for 16 tasks, shuffle-free (see header comment).
__device__ __forceinline__ float do_step(f32x4 (&al2)[4], const f32x4 (&er)[4],
                                         const bh4 (&Af)[4][4],
                                         float M2, int idxM) {
    bh4 Bf[4];
    #pragma unroll
    for (int kb = 0; kb < 4; ++kb) {
        PB2 pb;
        pb.i[0] = pack_bf16(fexp2(al2[kb].x - M2), fexp2(al2[kb].y - M2));
        pb.i[1] = pack_bf16(fexp2(al2[kb].z - M2), fexp2(al2[kb].w - M2));
        Bf[kb] = pb.v;
    }
    float M2n = 0.f;
    #pragma unroll
    for (int jt = 0; jt < 4; ++jt) {
        f32x4 d0 = {0.f, 0.f, 0.f, 0.f};
        f32x4 d1 = {0.f, 0.f, 0.f, 0.f};
        d0 = mfma16(Af[jt][0], Bf[0], d0);
        d1 = mfma16(Af[jt][1], Bf[1], d1);
        d0 = mfma16(Af[jt][2], Bf[2], d0);
        d1 = mfma16(Af[jt][3], Bf[3], d1);
        f32x4 d = d0 + d1;
        al2[jt].x = fmaf(er[jt].x, LOG2E, M2) + flog2(d.x);
        al2[jt].y = fmaf(er[jt].y, LOG2E, M2) + flog2(d.y);
        al2[jt].z = fmaf(er[jt].z, LOG2E, M2) + flog2(d.z);
        al2[jt].w = fmaf(er[jt].w, LOG2E, M2) + flog2(d.w);
        if (jt == 0) M2n = bpermf(idxM, al2[0].x);
    }
    return M2n;
}

__device__ __forceinline__ void load_row(f32x4 (&dst)[4],
                                         const float* __restrict__ eb,
                                         int t, int off) {
    const float* p = eb + (t & (TT - 1)) * SS + off;
    #pragma unroll
    for (int jt = 0; jt < 4; ++jt)
        dst[jt] = *(const f32x4*)(p + 16 * jt);
}

__global__ __launch_bounds__(64)
__attribute__((amdgpu_waves_per_eu(1, 1)))
void hmm_phaseA(const float* __restrict__ trans,
                const float* __restrict__ emis,
                float* __restrict__ out,
                float* __restrict__ ws_warm,
                float* __restrict__ ws_bound) {
    __shared__ float sm[16384];                // 48KB load slots + 16KB out

    const int lane = threadIdx.x;
    const int n = lane & 15, q = lane >> 4;
    const int rl = lane >> 4, ul = lane & 15;  // staging row / unit of lane
    const int w = blockIdx.x;                  // 0..511
    const int b = w >> 3, cg = w & 7;
    const int c = 16 * cg + n;                 // this lane's task
    const bool is_c0 = (c == 0);
    const int off = 4 * q;

    // A-fragments (K=16): A_jt,kb[m=n][k=4q+e] = exp(T[16kb+4q+e][16jt+n]).
    bh4 Af[4][4];
    #pragma unroll
    for (int jt = 0; jt < 4; ++jt)
        #pragma unroll
        for (int kb = 0; kb < 4; ++kb) {
            float v0 = __expf(trans[(16 * kb + 4 * q + 0) * SS + 16 * jt + n]);
            float v1 = __expf(trans[(16 * kb + 4 * q + 1) * SS + 16 * jt + n]);
            float v2 = __expf(trans[(16 * kb + 4 * q + 2) * SS + 16 * jt + n]);
            float v3 = __expf(trans[(16 * kb + 4 * q + 3) * SS + 16 * jt + n]);
            PB2 pb;
            pb.i[0] = pack_bf16(v0, v1);
            pb.i[1] = pack_bf16(v2, v3);
            Af[jt][kb] = pb.v;
        }

    const int idxM = n << 2;                   // broadcast lane p -> all q

    const float* eb = emis + (size_t)b * TT * SS;
    float*       ob = out  + (size_t)b * TT * SS;

    const int t0 = LL * c - (WARM + 1);        // per-lane; c=0 => -25

    // Init state + true alpha0 (pre-scaled so loads are consumed NOW,
    // keeping compiler vmcnt waits out of the pipelined loop).
    f32x4 al2[4], e0[4];
    load_row(al2, eb, t0, off);
    #pragma unroll
    for (int jt = 0; jt < 4; ++jt) al2[jt] = al2[jt] * LOG2E;
    load_row(e0, eb, 0, off);
    #pragma unroll
    for (int jt = 0; jt < 4; ++jt) e0[jt] = e0[jt] * LOG2E;

    float M2 = bpermf(idxM, al2[0].x);

    // ---- coalesced staging machinery -------------------------------------
    // issueL(pp, slot): 16 x global_load_lds_dwordx4. Instr i moves rows
    // 32*c_i-24+4*pp .. +3 (1KB contiguous, unit-permuted by ^i on the
    // SOURCE) into sm[slot*SLOTF + i*256 ...] (linear lane x 16B dest).
    auto issueL = [&](int pp, int slot) {
        #pragma unroll
        for (int i = 0; i < 16; ++i) {
            int ci = 16 * cg + i;
            int row = (32 * ci - 24 + 4 * pp + rl) & (TT - 1);
            const float* g = eb + row * SS + ((ul ^ i) << 2);
            __builtin_amdgcn_global_load_lds(
                (const __attribute__((address_space(1))) void*)g,
                (__attribute__((address_space(3))) void*)&sm[slot * SLOTF + i * 256],
                16, 0, 0);
        }
    };
    // er for step r from slot: task n, row r, units 4jt+q stored at ^n.
    auto read_er = [&](f32x4 (&er)[4], int sb, int r) {
        #pragma unroll
        for (int jt = 0; jt < 4; ++jt)
            er[jt] = *(const f32x4*)&sm[sb + n * 256 + r * 64 + ((((jt << 2) + q) ^ n) << 2)];
    };
    auto write_out = [&](int r, const f32x4 (&a)[4]) {
        #pragma unroll
        for (int jt = 0; jt < 4; ++jt)
            *(f32x4*)&sm[OUTF + n * 256 + r * 64 + ((((jt << 2) + q) ^ n) << 2)] = a[jt] * LN2F;
    };
    auto store_burst = [&](int pp) {
        #pragma unroll
        for (int i = 0; i < 16; ++i) {
            int ci = 16 * cg + i;
            f32x4 v = *(const f32x4*)&sm[OUTF + i * 256 + rl * 64 + (ul << 2)];
            int row = 32 * ci - 24 + 4 * pp + rl;     // main rows: no wrap
            *(f32x4*)(ob + (size_t)row * SS + ((ul ^ i) << 2)) = v;
        }
    };

    // Prologue: fill slots 0,1 (phases 0,1).
    issueL(0, 0);
    issueL(1, 1);

    // Warm phases p=0..5 (s = 1..24), no stores.
    #pragma unroll 1
    for (int p = 0; p < 6; ++p) {
        WAITV(16);                              // loads for slot p%3 done
        __builtin_amdgcn_sched_barrier(0);
        issueL(p + 2, (p + 2) % 3);
        const int sb = (p % 3) * SLOTF;
        #pragma unroll
        for (int r = 0; r < 4; ++r) {
            f32x4 er[4];
            read_er(er, sb, r);
            M2 = do_step(al2, er, Af, M2, idxM);
        }
    }
    // Boundary (uncorrected) alpha at t = 32c-1: lane n (q=0) holds j=0.
    if (lane < 16)
        ws_warm[b * C_CH + 16 * cg + lane] = al2[0].x * LN2F;

    // Phase 6 (s = 25..28): first main phase, c0 override at r=0.
    {
        WAITV(16);
        __builtin_amdgcn_sched_barrier(0);
        issueL(8, 2);                           // 8 % 3 == 2
        const int sb = 0;                       // 6 % 3 == 0
        #pragma unroll
        for (int r = 0; r < 4; ++r) {
            f32x4 er[4];
            read_er(er, sb, r);
            M2 = do_step(al2, er, Af, M2, idxM);
            if (r == 0) {
                if (is_c0) {
                    #pragma unroll
                    for (int jt = 0; jt < 4; ++jt) al2[jt] = e0[jt];
                }
                if (cg == 0)                    // wave-uniform M2 refresh
                    M2 = bpermf(idxM, al2[0].x);
            }
            write_out(r, al2);
        }
        store_burst(6);
    }

    // Main phases p=7..13 (s = 29..56).
    #pragma unroll 1
    for (int p = 7; p < 14; ++p) {
        WAITV(32);                              // loads for slot p%3 done
        __builtin_amdgcn_sched_barrier(0);
        if (p <= 11)
            issueL(p + 2, (p + 2) % 3);
        const int sb = (p % 3) * SLOTF;
        #pragma unroll
        for (int r = 0; r < 4; ++r) {
            f32x4 er[4];
            read_er(er, sb, r);
            M2 = do_step(al2, er, Af, M2, idxM);
            write_out(r, al2);
        }
        store_burst(p);
    }

    if (lane < 16)
        ws_bound[b * C_CH + 16 * cg + lane] = al2[0].x * LN2F;
}

// Correction: redundant per-block prefix sum of deltas (ws scalars only,
// LDS Hillis-Steele over C_CH=128), float4 RMW of the chunk, block
// (b, C-1) emits log_Z.
__global__ __launch_bounds__(256)
void hmm_phaseC(float* __restrict__ out,
                const float* __restrict__ ws_warm,
                const float* __restrict__ ws_bound) {
    const int b = blockIdx.x, c = blockIdx.y, tid = threadIdx.x;
    __shared__ float sd[C_CH];

    if (tid < C_CH) {
        float d = 0.f;
        if (tid > 0)
            d = ws_bound[b * C_CH + tid - 1] - ws_warm[b * C_CH + tid];
        sd[tid] = d;
    }
    __syncthreads();
    #pragma unroll
    for (int off = 1; off < C_CH; off <<= 1) {
        float v = 0.f;
        if (tid >= off && tid < C_CH) v = sd[tid - off];
        __syncthreads();
        if (tid >= off && tid < C_CH) sd[tid] += v;
        __syncthreads();
    }
    const float delta = sd[c];

    float4* p4 = (float4*)(out + (size_t)b * TT * SS + (size_t)c * LL * SS);
    float4 last;
    #pragma unroll
    for (int i = 0; i < 2; ++i) {
        int idx = tid + 256 * i;               // 2*256 = 512 float4 = LL*SS
        float4 v = p4[idx];
        v.x += delta; v.y += delta; v.z += delta; v.w += delta;
        p4[idx] = v;
        last = v;                              // i==1, tid 240..255 => row T-1
    }

    if (c == C_CH - 1 && tid >= 240) {
        float mx = fmaxf(fmaxf(last.x, last.y), fmaxf(last.z, last.w));
        #pragma unroll
        for (int off = 8; off >= 1; off >>= 1)
            mx = fmaxf(mx, __shfl_xor(mx, off, 64));
        float sv = __expf(last.x - mx) + __expf(last.y - mx)
                 + __expf(last.z - mx) + __expf(last.w - mx);
        #pragma unroll
        for (int off = 8; off >= 1; off >>= 1)
            sv += __shfl_xor(sv, off, 64);
        if (tid == 240)
            out[(size_t)BB * TT * SS + b] = mx + __logf(sv);
    }
}

extern "C" void kernel_launch(void* const* d_in, const int* in_sizes, int n_in,
                              void* d_out, int out_size, void* d_ws, size_t ws_size,
                              hipStream_t stream) {
    const float* trans = (const float*)d_in[0];   // (S,S)
    const float* emis  = (const float*)d_in[1];   // (B,T,S)
    // d_in[2] = seq_lens — unused by the reference.
    float* out = (float*)d_out;                   // alpha (B,T,S) ++ log_Z (B,)

    float* ws_warm  = (float*)d_ws;               // B*C floats
    float* ws_bound = ws_warm + BB * C_CH;        // B*C floats

    hmm_phaseA<<<dim3(BB * 8), dim3(64), 0, stream>>>(trans, emis, out,
                                                      ws_warm, ws_bound);
    hmm_phaseC<<<dim3(BB, C_CH), dim3(256), 0, stream>>>(out, ws_warm, ws_bound);
}

// Round 4
// 153.466 us; speedup vs baseline: 1.0982x; 1.0103x over previous
//
#include <hip/hip_runtime.h>
#include <hip/hip_bf16.h>

// HMM forward, chunk-parallel + MFMA. B=64, T=4096, S=64.
//
// R4 change vs R2/R3: LINEAR-SPACE recurrence. R1-R3 post-mortems showed
// the step is per-wave issue+chain bound (~850 cy/CU-step saturation;
// memory arrangement irrelevant). Old step carried log-space state:
// 16 exp2 + 16 log2 + bpermute ON the serial chain (~250 cy chain,
// ~500 cy issue). New step keeps v = 2^(alpha*log2e - S_t) linear:
//   A-frags: Ahat = exp(T)*2^-6 (constant rescale folded in, no max/bcast)
//   step:    d[jt] = sum_kb mfma16(Ahat, pack_bf16(v)); v' = d * exp(emis)
//   chain:   mul -> cvt_pk -> 2xMFMA -> add  (~60 cy, no trans, no bperm)
//   S_t += 6 per step (implicit); drift |log2 v| <= ~85 bits at 4 sigma
//   over 56 steps -- safe in fp32/bf16 exponent range; bf16 relative
//   precision is scale-free (same accuracy as normalized-u scheme).
// exp(emis) is off-chain (depends only on prefetched rows); outputs
// alpha = log2(v)*ln2 + (6s+phi)*ln2 are off-chain; WARM steps need no
// log at all. phi = -150 for chunk 0 (exactness of the t=0 anchor),
// 0 elsewhere (absorbed by phaseC's per-chunk additive correction).
//
// Geometry (R2): LL=32, C_CH=128, WARM=24, 512 waves (2/CU), register
// prefetch depth PF=8. Phase C: scan + float4 RMW + log_Z (unchanged).

#define BB 64
#define TT 4096
#define SS 64
#define C_CH 128
#define LL 32
#define WARM 24
#define PF 8

typedef __attribute__((ext_vector_type(4))) short bh4;
typedef __attribute__((ext_vector_type(4))) float f32x4;

#define LOG2E 1.44269504088896340736f
#define LN2F  0.69314718055994530942f

__device__ __forceinline__ float fexp2(float x) {
#if __has_builtin(__builtin_amdgcn_exp2f)
    return __builtin_amdgcn_exp2f(x);
#else
    return exp2f(x);
#endif
}
__device__ __forceinline__ float flog2(float x) {
#if __has_builtin(__builtin_amdgcn_logf)
    return __builtin_amdgcn_logf(x);
#else
    return log2f(x);
#endif
}
__device__ __forceinline__ int pack_bf16(float x, float y) {
    __hip_bfloat162 h = __float22bfloat162_rn(make_float2(x, y));
    int r; __builtin_memcpy(&r, &h, 4); return r;
}
union PB2 { int i[2]; bh4 v; };

__device__ __forceinline__ f32x4 mfma16(bh4 a, bh4 b, f32x4 c) {
#if __has_builtin(__builtin_amdgcn_mfma_f32_16x16x16bf16_1k)
    return __builtin_amdgcn_mfma_f32_16x16x16bf16_1k(a, b, c, 0, 0, 0);
#else
    asm("v_mfma_f32_16x16x16_bf16 %0, %1, %2, %0" : "+v"(c) : "v"(a), "v"(b));
    return c;
#endif
}

// One linear-space recurrence step for 16 tasks.
//   vv[kb] holds v[task=lane&15][j = 16*kb + 4q + r]  (B-layout == D-layout)
//   eE[jt] = exp(emis_row[j]) elementwise (2^-6 folded into Af).
__device__ __forceinline__ void do_step(f32x4 (&vv)[4], const f32x4 (&eE)[4],
                                        const bh4 (&Af)[4][4]) {
    bh4 Bf[4];
    #pragma unroll
    for (int kb = 0; kb < 4; ++kb) {
        PB2 pb;
        pb.i[0] = pack_bf16(vv[kb].x, vv[kb].y);
        pb.i[1] = pack_bf16(vv[kb].z, vv[kb].w);
        Bf[kb] = pb.v;
    }
    #pragma unroll
    for (int jt = 0; jt < 4; ++jt) {
        f32x4 d0 = {0.f, 0.f, 0.f, 0.f};
        f32x4 d1 = {0.f, 0.f, 0.f, 0.f};
        d0 = mfma16(Af[jt][0], Bf[0], d0);
        d1 = mfma16(Af[jt][1], Bf[1], d1);
        d0 = mfma16(Af[jt][2], Bf[2], d0);
        d1 = mfma16(Af[jt][3], Bf[3], d1);
        f32x4 d = d0 + d1;
        vv[jt] = d * eE[jt];
    }
}

__device__ __forceinline__ void load_row(f32x4 (&dst)[4],
                                         const float* __restrict__ eb,
                                         int t, int off) {
    const float* p = eb + (t & (TT - 1)) * SS + off;
    #pragma unroll
    for (int jt = 0; jt < 4; ++jt)
        dst[jt] = *(const f32x4*)(p + 16 * jt);
}

__global__ __launch_bounds__(64)
__attribute__((amdgpu_waves_per_eu(1, 1)))
void hmm_phaseA(const float* __restrict__ trans,
                const float* __restrict__ emis,
                float* __restrict__ out,
                float* __restrict__ ws_warm,
                float* __restrict__ ws_bound) {
    const int lane = threadIdx.x;
    const int n = lane & 15, q = lane >> 4;
    const int w = blockIdx.x;                  // 0..511
    const int b = w >> 3, cg = w & 7;
    const int c = 16 * cg + n;                 // this lane's task
    const bool is_c0 = (c == 0);
    const int off = 4 * q;

    // A-fragments (K=16): A_jt,kb[m=n][k=4q+e] = exp(T[16kb+4q+e][16jt+n])
    // with the constant per-step rescale 2^-6 folded in.
    bh4 Af[4][4];
    #pragma unroll
    for (int jt = 0; jt < 4; ++jt)
        #pragma unroll
        for (int kb = 0; kb < 4; ++kb) {
            float v0 = __expf(trans[(16 * kb + 4 * q + 0) * SS + 16 * jt + n]) * 0.015625f;
            float v1 = __expf(trans[(16 * kb + 4 * q + 1) * SS + 16 * jt + n]) * 0.015625f;
            float v2 = __expf(trans[(16 * kb + 4 * q + 2) * SS + 16 * jt + n]) * 0.015625f;
            float v3 = __expf(trans[(16 * kb + 4 * q + 3) * SS + 16 * jt + n]) * 0.015625f;
            PB2 pb;
            pb.i[0] = pack_bf16(v0, v1);
            pb.i[1] = pack_bf16(v2, v3);
            Af[jt][kb] = pb.v;
        }

    const float* eb = emis + (size_t)b * TT * SS;
    float*       ob = out  + (size_t)b * TT * SS;

    const int t0 = LL * c - (WARM + 1);        // per-lane; c=0 => -25

    // Per-lane output constant: alpha = log2(v)*ln2 + (6s + phi)*ln2.
    // phi = -150 (= -6*25) for chunk 0 so its t=0 anchor is EXACT.
    const float cL = is_c0 ? (-150.0f * LN2F) : 0.0f;

    // Init: v = exp(emis[t0]) (pseudo; garbage-warm for c=0), plus the
    // true alpha0 row pre-exped for the c0 override.
    f32x4 vv[4], e0v[4], ebuf[PF][4];
    {
        f32x4 a0[4], z0[4];
        load_row(a0, eb, t0, off);
        load_row(z0, eb, 0, off);
        #pragma unroll
        for (int jt = 0; jt < 4; ++jt) {
            vv[jt].x = fexp2(a0[jt].x * LOG2E);
            vv[jt].y = fexp2(a0[jt].y * LOG2E);
            vv[jt].z = fexp2(a0[jt].z * LOG2E);
            vv[jt].w = fexp2(a0[jt].w * LOG2E);
            e0v[jt].x = fexp2(z0[jt].x * LOG2E);
            e0v[jt].y = fexp2(z0[jt].y * LOG2E);
            e0v[jt].z = fexp2(z0[jt].z * LOG2E);
            e0v[jt].w = fexp2(z0[jt].w * LOG2E);
        }
    }
    #pragma unroll
    for (int k = 0; k < PF; ++k) load_row(ebuf[k], eb, t0 + 1 + k, off);

    // Warm-up: s = 1..24 (3 groups of PF=8), no stores, NO log path.
    #pragma unroll 1
    for (int g = 0; g < 3; ++g) {
        #pragma unroll
        for (int k = 0; k < PF; ++k) {
            int s = PF * g + k + 1;
            f32x4 eE[4];
            #pragma unroll
            for (int jt = 0; jt < 4; ++jt) {
                eE[jt].x = fexp2(ebuf[k][jt].x * LOG2E);
                eE[jt].y = fexp2(ebuf[k][jt].y * LOG2E);
                eE[jt].z = fexp2(ebuf[k][jt].z * LOG2E);
                eE[jt].w = fexp2(ebuf[k][jt].w * LOG2E);
            }
            load_row(ebuf[k], eb, t0 + s + PF, off);
            do_step(vv, eE, Af);
        }
    }
    // Boundary (uncorrected) alpha at t = 32c-1 (s=24): lane n holds j=0.
    if (lane < 16)
        ws_warm[b * C_CH + 16 * cg + lane] =
            fmaf(flog2(vv[0].x), LN2F, 144.0f * LN2F + cL);

    // Main: s = 25..56, writes t = t0+s = 32c .. 32c+31.
    #pragma unroll 1
    for (int g = 0; g < 4; ++g) {
        #pragma unroll
        for (int k = 0; k < PF; ++k) {
            int s = WARM + 1 + PF * g + k;
            f32x4 eE[4];
            #pragma unroll
            for (int jt = 0; jt < 4; ++jt) {
                eE[jt].x = fexp2(ebuf[k][jt].x * LOG2E);
                eE[jt].y = fexp2(ebuf[k][jt].y * LOG2E);
                eE[jt].z = fexp2(ebuf[k][jt].z * LOG2E);
                eE[jt].w = fexp2(ebuf[k][jt].w * LOG2E);
            }
            load_row(ebuf[k], eb, t0 + s + PF, off);
            do_step(vv, eE, Af);
            if (k == 0 && g == 0 && is_c0) {
                // chunk 0: replace garbage warm result with true alpha0
                // (phi = -150 makes the written value exactly emis[0]).
                #pragma unroll
                for (int jt = 0; jt < 4; ++jt) vv[jt] = e0v[jt];
            }
            const float cs = 6.0f * (float)s * LN2F + cL;
            float* p = ob + (t0 + s) * SS + off;
            #pragma unroll
            for (int jt = 0; jt < 4; ++jt) {
                f32x4 a;
                a.x = fmaf(flog2(vv[jt].x), LN2F, cs);
                a.y = fmaf(flog2(vv[jt].y), LN2F, cs);
                a.z = fmaf(flog2(vv[jt].z), LN2F, cs);
                a.w = fmaf(flog2(vv[jt].w), LN2F, cs);
                *(f32x4*)(p + 16 * jt) = a;
            }
        }
    }
    if (lane < 16)
        ws_bound[b * C_CH + 16 * cg + lane] =
            fmaf(flog2(vv[0].x), LN2F, 336.0f * LN2F + cL);
}

// Correction: redundant per-block prefix sum of deltas (ws scalars only,
// LDS Hillis-Steele over C_CH=128), float4 RMW of the chunk, block
// (b, C-1) emits log_Z.
__global__ __launch_bounds__(256)
void hmm_phaseC(float* __restrict__ out,
                const float* __restrict__ ws_warm,
                const float* __restrict__ ws_bound) {
    const int b = blockIdx.x, c = blockIdx.y, tid = threadIdx.x;
    __shared__ float sd[C_CH];

    if (tid < C_CH) {
        float d = 0.f;
        if (tid > 0)
            d = ws_bound[b * C_CH + tid - 1] - ws_warm[b * C_CH + tid];
        sd[tid] = d;
    }
    __syncthreads();
    #pragma unroll
    for (int off = 1; off < C_CH; off <<= 1) {
        float v = 0.f;
        if (tid >= off && tid < C_CH) v = sd[tid - off];
        __syncthreads();
        if (tid >= off && tid < C_CH) sd[tid] += v;
        __syncthreads();
    }
    const float delta = sd[c];

    float4* p4 = (float4*)(out + (size_t)b * TT * SS + (size_t)c * LL * SS);
    float4 last;
    #pragma unroll
    for (int i = 0; i < 2; ++i) {
        int idx = tid + 256 * i;               // 2*256 = 512 float4 = LL*SS
        float4 v = p4[idx];
        v.x += delta; v.y += delta; v.z += delta; v.w += delta;
        p4[idx] = v;
        last = v;                              // i==1, tid 240..255 => row T-1
    }

    if (c == C_CH - 1 && tid >= 240) {
        float mx = fmaxf(fmaxf(last.x, last.y), fmaxf(last.z, last.w));
        #pragma unroll
        for (int off = 8; off >= 1; off >>= 1)
            mx = fmaxf(mx, __shfl_xor(mx, off, 64));
        float sv = __expf(last.x - mx) + __expf(last.y - mx)
                 + __expf(last.z - mx) + __expf(last.w - mx);
        #pragma unroll
        for (int off = 8; off >= 1; off >>= 1)
            sv += __shfl_xor(sv, off, 64);
        if (tid == 240)
            out[(size_t)BB * TT * SS + b] = mx + __logf(sv);
    }
}

extern "C" void kernel_launch(void* const* d_in, const int* in_sizes, int n_in,
                              void* d_out, int out_size, void* d_ws, size_t ws_size,
                              hipStream_t stream) {
    const float* trans = (const float*)d_in[0];   // (S,S)
    const float* emis  = (const float*)d_in[1];   // (B,T,S)
    // d_in[2] = seq_lens — unused by the reference.
    float* out = (float*)d_out;                   // alpha (B,T,S) ++ log_Z (B,)

    float* ws_warm  = (float*)d_ws;               // B*C floats
    float* ws_bound = ws_warm + BB * C_CH;        // B*C floats

    hmm_phaseA<<<dim3(BB * 8), dim3(64), 0, stream>>>(trans, emis, out,
                                                      ws_warm, ws_bound);
    hmm_phaseC<<<dim3(BB, C_CH), dim3(256), 0, stream>>>(out, ws_warm, ws_bound);
}

// Round 5
// 146.242 us; speedup vs baseline: 1.1525x; 1.0494x over previous
//
#include <hip/hip_runtime.h>
#include <hip/hip_bf16.h>

// HMM forward, chunk-parallel + MFMA. B=64, T=4096, S=64.
//
// R5 change vs R4: restructure the output data flow. R2-R4 showed phaseA
// time (~44us) is invariant to compute (VALUBusy fell with lighter chain)
// -> pinned by scattered 16x64B load/store streams at ~3 TB/s; and the
// dur_us residue decomposes as ~82us harness poison-fills + phaseA +
// phaseC(~27us, 134MB RMW of out). Changes:
//   - phaseA stores bf16(v) rows into a wave-private SEQUENTIAL 64KB slab
//     of workspace (ws2, 33.5MB total). Stores scatter only within the
//     wave's own 64KB window -> L2-resident; slab stream sequential at
//     DRAM. phaseA loses the whole log path (16 log2 + 16 fma per step)
//     and the 67MB scattered alpha-store stream.
//   - phaseC: scan -> read ws2 (4KB contig per block, L3-warm) ->
//     alpha = log2(v)*ln2 + 6(r+25)*ln2 + phi + delta -> WRITE-ONLY 8KB
//     contig per chunk into out -> log_Z. out RMW (134MB) -> write 67MB.
//
// Linear-space recurrence (R4): v = 2^(alpha*log2e - 6s), Ahat=exp(T)*2^-6.
//   step: d[jt] = sum_kb mfma16(Ahat, pack_bf16(v)); v' = d * exp(emis)
//   drift |log2 v| <= ~85 bits at 4 sigma over 56 steps (fp32-safe);
//   bf16 relative precision is scale-free. phi = -150*ln2 for chunk 0
//   (exact t=0 anchor), 0 elsewhere (absorbed by phaseC correction).
//
// Geometry: LL=32, C_CH=128, WARM=24, 512 waves (2/CU), reg prefetch PF=8.

#define BB 64
#define TT 4096
#define SS 64
#define C_CH 128
#define LL 32
#define WARM 24
#define PF 8
#define WSLAB 32768          // ushorts per wave slab (16 tasks x 32 rows x 64)

typedef __attribute__((ext_vector_type(4))) short bh4;
typedef __attribute__((ext_vector_type(4))) float f32x4;
typedef __attribute__((ext_vector_type(4))) unsigned short us4;

#define LOG2E 1.44269504088896340736f
#define LN2F  0.69314718055994530942f

__device__ __forceinline__ float fexp2(float x) {
#if __has_builtin(__builtin_amdgcn_exp2f)
    return __builtin_amdgcn_exp2f(x);
#else
    return exp2f(x);
#endif
}
__device__ __forceinline__ float flog2(float x) {
#if __has_builtin(__builtin_amdgcn_logf)
    return __builtin_amdgcn_logf(x);
#else
    return log2f(x);
#endif
}
__device__ __forceinline__ int pack_bf16(float x, float y) {
    __hip_bfloat162 h = __float22bfloat162_rn(make_float2(x, y));
    int r; __builtin_memcpy(&r, &h, 4); return r;
}
__device__ __forceinline__ float bf_to_f32(unsigned short u) {
    unsigned int w = ((unsigned int)u) << 16;
    float f; __builtin_memcpy(&f, &w, 4); return f;
}
union PB2 { int i[2]; bh4 v; us4 u; };

__device__ __forceinline__ f32x4 mfma16(bh4 a, bh4 b, f32x4 c) {
#if __has_builtin(__builtin_amdgcn_mfma_f32_16x16x16bf16_1k)
    return __builtin_amdgcn_mfma_f32_16x16x16bf16_1k(a, b, c, 0, 0, 0);
#else
    asm("v_mfma_f32_16x16x16_bf16 %0, %1, %2, %0" : "+v"(c) : "v"(a), "v"(b));
    return c;
#endif
}

// One linear-space recurrence step for 16 tasks.
//   vv[kb] holds v[task=lane&15][j = 16*kb + 4q + r]  (B-layout == D-layout)
//   eE[jt] = exp(emis_row[j]) elementwise (2^-6 folded into Af).
__device__ __forceinline__ void do_step(f32x4 (&vv)[4], const f32x4 (&eE)[4],
                                        const bh4 (&Af)[4][4]) {
    bh4 Bf[4];
    #pragma unroll
    for (int kb = 0; kb < 4; ++kb) {
        PB2 pb;
        pb.i[0] = pack_bf16(vv[kb].x, vv[kb].y);
        pb.i[1] = pack_bf16(vv[kb].z, vv[kb].w);
        Bf[kb] = pb.v;
    }
    #pragma unroll
    for (int jt = 0; jt < 4; ++jt) {
        f32x4 d0 = {0.f, 0.f, 0.f, 0.f};
        f32x4 d1 = {0.f, 0.f, 0.f, 0.f};
        d0 = mfma16(Af[jt][0], Bf[0], d0);
        d1 = mfma16(Af[jt][1], Bf[1], d1);
        d0 = mfma16(Af[jt][2], Bf[2], d0);
        d1 = mfma16(Af[jt][3], Bf[3], d1);
        f32x4 d = d0 + d1;
        vv[jt] = d * eE[jt];
    }
}

__device__ __forceinline__ void load_row(f32x4 (&dst)[4],
                                         const float* __restrict__ eb,
                                         int t, int off) {
    const float* p = eb + (t & (TT - 1)) * SS + off;
    #pragma unroll
    for (int jt = 0; jt < 4; ++jt)
        dst[jt] = *(const f32x4*)(p + 16 * jt);
}

__global__ __launch_bounds__(64)
__attribute__((amdgpu_waves_per_eu(1, 1)))
void hmm_phaseA(const float* __restrict__ trans,
                const float* __restrict__ emis,
                unsigned short* __restrict__ wsv,
                float* __restrict__ ws_warm,
                float* __restrict__ ws_bound) {
    const int lane = threadIdx.x;
    const int n = lane & 15, q = lane >> 4;
    const int w = blockIdx.x;                  // 0..511
    const int b = w >> 3, cg = w & 7;
    const int c = 16 * cg + n;                 // this lane's task
    const bool is_c0 = (c == 0);
    const int off = 4 * q;

    // A-fragments (K=16): A_jt,kb[m=n][k=4q+e] = exp(T[16kb+4q+e][16jt+n])
    // with the constant per-step rescale 2^-6 folded in.
    bh4 Af[4][4];
    #pragma unroll
    for (int jt = 0; jt < 4; ++jt)
        #pragma unroll
        for (int kb = 0; kb < 4; ++kb) {
            float v0 = __expf(trans[(16 * kb + 4 * q + 0) * SS + 16 * jt + n]) * 0.015625f;
            float v1 = __expf(trans[(16 * kb + 4 * q + 1) * SS + 16 * jt + n]) * 0.015625f;
            float v2 = __expf(trans[(16 * kb + 4 * q + 2) * SS + 16 * jt + n]) * 0.015625f;
            float v3 = __expf(trans[(16 * kb + 4 * q + 3) * SS + 16 * jt + n]) * 0.015625f;
            PB2 pb;
            pb.i[0] = pack_bf16(v0, v1);
            pb.i[1] = pack_bf16(v2, v3);
            Af[jt][kb] = pb.v;
        }

    const float* eb = emis + (size_t)b * TT * SS;
    unsigned short* wslab = wsv + (size_t)w * WSLAB;

    const int t0 = LL * c - (WARM + 1);        // per-lane; c=0 => -25

    // phi = -150*ln2 for chunk 0 so its t=0 anchor is EXACT.
    const float cL = is_c0 ? (-150.0f * LN2F) : 0.0f;

    // Init: v = exp(emis[t0]) (pseudo; garbage-warm for c=0), plus the
    // true alpha0 row pre-exped for the c0 override.
    f32x4 vv[4], e0v[4], ebuf[PF][4];
    {
        f32x4 a0[4], z0[4];
        load_row(a0, eb, t0, off);
        load_row(z0, eb, 0, off);
        #pragma unroll
        for (int jt = 0; jt < 4; ++jt) {
            vv[jt].x = fexp2(a0[jt].x * LOG2E);
            vv[jt].y = fexp2(a0[jt].y * LOG2E);
            vv[jt].z = fexp2(a0[jt].z * LOG2E);
            vv[jt].w = fexp2(a0[jt].w * LOG2E);
            e0v[jt].x = fexp2(z0[jt].x * LOG2E);
            e0v[jt].y = fexp2(z0[jt].y * LOG2E);
            e0v[jt].z = fexp2(z0[jt].z * LOG2E);
            e0v[jt].w = fexp2(z0[jt].w * LOG2E);
        }
    }
    #pragma unroll
    for (int k = 0; k < PF; ++k) load_row(ebuf[k], eb, t0 + 1 + k, off);

    // Warm-up: s = 1..24 (3 groups of PF=8), no stores, no log path.
    #pragma unroll 1
    for (int g = 0; g < 3; ++g) {
        #pragma unroll
        for (int k = 0; k < PF; ++k) {
            int s = PF * g + k + 1;
            f32x4 eE[4];
            #pragma unroll
            for (int jt = 0; jt < 4; ++jt) {
                eE[jt].x = fexp2(ebuf[k][jt].x * LOG2E);
                eE[jt].y = fexp2(ebuf[k][jt].y * LOG2E);
                eE[jt].z = fexp2(ebuf[k][jt].z * LOG2E);
                eE[jt].w = fexp2(ebuf[k][jt].w * LOG2E);
            }
            load_row(ebuf[k], eb, t0 + s + PF, off);
            do_step(vv, eE, Af);
        }
    }
    // Boundary (uncorrected) alpha at t = 32c-1 (s=24): lane n holds j=0.
    if (lane < 16)
        ws_warm[b * C_CH + 16 * cg + lane] =
            fmaf(flog2(vv[0].x), LN2F, 144.0f * LN2F + cL);

    // Main: s = 25..56; store bf16(v) row (s-25) into the wave slab.
    // Slab layout: [task n][row r][j] ushort, j-linear -> lane (n,q)
    // stores 4x us4 (8B each) at j = 16kb+4q. Scatter stays inside the
    // wave's 64KB window (L2-resident); slab stream sequential at DRAM.
    #pragma unroll 1
    for (int g = 0; g < 4; ++g) {
        #pragma unroll
        for (int k = 0; k < PF; ++k) {
            int s = WARM + 1 + PF * g + k;
            f32x4 eE[4];
            #pragma unroll
            for (int jt = 0; jt < 4; ++jt) {
                eE[jt].x = fexp2(ebuf[k][jt].x * LOG2E);
                eE[jt].y = fexp2(ebuf[k][jt].y * LOG2E);
                eE[jt].z = fexp2(ebuf[k][jt].z * LOG2E);
                eE[jt].w = fexp2(ebuf[k][jt].w * LOG2E);
            }
            load_row(ebuf[k], eb, t0 + s + PF, off);
            do_step(vv, eE, Af);
            if (k == 0 && g == 0 && is_c0) {
                // chunk 0: replace garbage warm result with true alpha0
                // (phi = -150*ln2 makes the decoded value exactly emis[0]).
                #pragma unroll
                for (int jt = 0; jt < 4; ++jt) vv[jt] = e0v[jt];
            }
            unsigned short* wp = wslab + (n * 32 + (s - (WARM + 1))) * 64 + 4 * q;
            #pragma unroll
            for (int kb = 0; kb < 4; ++kb) {
                PB2 pb;
                pb.i[0] = pack_bf16(vv[kb].x, vv[kb].y);
                pb.i[1] = pack_bf16(vv[kb].z, vv[kb].w);
                *(us4*)(wp + 16 * kb) = pb.u;
            }
        }
    }
    if (lane < 16)
        ws_bound[b * C_CH + 16 * cg + lane] =
            fmaf(flog2(vv[0].x), LN2F, 336.0f * LN2F + cL);
}

// phaseC: per-chunk block (b,c). Redundant prefix-scan of boundary deltas,
// then read the chunk's bf16 v from ws2 (4KB contiguous, L3-warm), decode
// alpha = log2(v)*ln2 + 6*(r+25)*ln2 + phi + delta, write 8KB contiguous
// f32 into out. Block (b, C-1) also emits log_Z from its corrected last row.
__global__ __launch_bounds__(256)
void hmm_phaseC(float* __restrict__ out,
                const unsigned short* __restrict__ wsv,
                const float* __restrict__ ws_warm,
                const float* __restrict__ ws_bound) {
    const int b = blockIdx.x, c = blockIdx.y, tid = threadIdx.x;
    __shared__ float sd[C_CH];

    if (tid < C_CH) {
        float d = 0.f;
        if (tid > 0)
            d = ws_bound[b * C_CH + tid - 1] - ws_warm[b * C_CH + tid];
        sd[tid] = d;
    }
    __syncthreads();
    #pragma unroll
    for (int off = 1; off < C_CH; off <<= 1) {
        float v = 0.f;
        if (tid >= off && tid < C_CH) v = sd[tid - off];
        __syncthreads();
        if (tid >= off && tid < C_CH) sd[tid] += v;
        __syncthreads();
    }
    const float delta = sd[c];

    // This chunk's slab region: wave (b*8 + c>>4), task c&15.
    const int cg = c >> 4, n = c & 15;
    const unsigned short* src =
        wsv + (size_t)(b * 8 + cg) * WSLAB + n * 2048 + tid * 8;
    const int r = tid >> 3, col0 = (tid & 7) * 8;

    us4 u0 = *(const us4*)(src);
    us4 u1 = *(const us4*)(src + 4);

    const float cs = fmaf(6.0f * (float)(r + 25), LN2F,
                          (c == 0 ? -150.0f * LN2F : 0.0f) + delta);
    float a[8];
    #pragma unroll
    for (int i = 0; i < 4; ++i) {
        a[i]     = fmaf(flog2(bf_to_f32(u0[i])), LN2F, cs);
        a[4 + i] = fmaf(flog2(bf_to_f32(u1[i])), LN2F, cs);
    }

    float* dst = out + (size_t)b * TT * SS + (size_t)(32 * c + r) * SS + col0;
    *(f32x4*)(dst)     = *(f32x4*)&a[0];
    *(f32x4*)(dst + 4) = *(f32x4*)&a[4];

    // log_Z from the corrected last row (r == 31 -> tid 248..255, one wave).
    if (c == C_CH - 1 && tid >= 248) {
        float mx = a[0];
        #pragma unroll
        for (int i = 1; i < 8; ++i) mx = fmaxf(mx, a[i]);
        #pragma unroll
        for (int off = 4; off >= 1; off >>= 1)
            mx = fmaxf(mx, __shfl_xor(mx, off, 64));
        float sv = 0.f;
        #pragma unroll
        for (int i = 0; i < 8; ++i) sv += __expf(a[i] - mx);
        #pragma unroll
        for (int off = 4; off >= 1; off >>= 1)
            sv += __shfl_xor(sv, off, 64);
        if (tid == 248)
            out[(size_t)BB * TT * SS + b] = mx + __logf(sv);
    }
}

extern "C" void kernel_launch(void* const* d_in, const int* in_sizes, int n_in,
                              void* d_out, int out_size, void* d_ws, size_t ws_size,
                              hipStream_t stream) {
    const float* trans = (const float*)d_in[0];   // (S,S)
    const float* emis  = (const float*)d_in[1];   // (B,T,S)
    // d_in[2] = seq_lens — unused by the reference.
    float* out = (float*)d_out;                   // alpha (B,T,S) ++ log_Z (B,)

    float* ws_warm  = (float*)d_ws;               // B*C floats
    float* ws_bound = ws_warm + BB * C_CH;        // B*C floats
    unsigned short* wsv =
        (unsigned short*)(ws_bound + BB * C_CH);  // 512 * WSLAB ushorts

    hmm_phaseA<<<dim3(BB * 8), dim3(64), 0, stream>>>(trans, emis, wsv,
                                                      ws_warm, ws_bound);
    hmm_phaseC<<<dim3(BB, C_CH), dim3(256), 0, stream>>>(out, wsv,
                                                         ws_warm, ws_bound);
}